// Round 8
// baseline (282.104 us; speedup 1.0000x reference)
//
#include <hip/hip_runtime.h>
#include <hip/hip_cooperative_groups.h>
#include <type_traits>

namespace cg = cooperative_groups;

#define B_   32
#define T_   512
#define D_   512
#define F_   256
#define MEL  4096
#define EPS_ 1e-5f

typedef __attribute__((ext_vector_type(8))) short bf16x8;
typedef __attribute__((ext_vector_type(4))) float f32x4;

#define GLL16(gp, lp) \
    __builtin_amdgcn_global_load_lds((const __attribute__((address_space(1))) void*)(gp), \
                                     (__attribute__((address_space(3))) void*)(lp), 16, 0, 0)
#define BARRIER() do { asm volatile("" ::: "memory"); __builtin_amdgcn_s_barrier(); \
                       asm volatile("" ::: "memory"); } while (0)
#define MEMPIN() asm volatile("" ::: "memory")

__device__ inline unsigned short f2bf(float f) {
    unsigned u = __float_as_uint(f);
    unsigned r = (u + 0x7fff + ((u >> 16) & 1)) >> 16;   // RNE
    return (unsigned short)r;
}

struct SharedMem {
    alignas(16) char xs_raw[(64 + 2) * 512 * 2];   // 67.5 KB: conv A tile; P0 lcum
    alignas(16) unsigned short xsB[2 * 16384];      // 64 KB: B double buffer
    float red[64][8];                               // 2 KB: LN stats
    float redD[64][4];                              // 1 KB: dur partials; P0 wave sums
};

// ---------------------------------------------------------------------------
// Conv1d(K=3,SAME)+bias+LN+ReLU via bf16 MFMA with gather rows riding the same
// counted-vmcnt pipeline. Body order [stageB G_{p+2}][storeSet S_p][loadSet
// L_{p+3}] so phase-top waits drain only through G_p (stores get >=1 phase of
// slack; gather-load->store reg deps are compiler-waited). Masked rows skip
// the load (fewer outstanding ops only strengthens the vmcnt guarantee).
// ---------------------------------------------------------------------------
template<int IN_D, typename InT, bool FUSE_DUR, int GP, int GBASE>
__device__ void conv_phase(SharedMem& sm, const InT* __restrict__ x,
                           const unsigned short* __restrict__ wT,
                           const float* __restrict__ bias, const float* __restrict__ gamma,
                           const float* __restrict__ beta, unsigned short* __restrict__ outp,
                           const float* __restrict__ wl, const float* __restrict__ bl,
                           float* __restrict__ dur,
                           const float* __restrict__ xf, const int* __restrict__ gidx,
                           float* __restrict__ gout)
{
    constexpr int MT = 64;
    constexpr int KT = 3 * IN_D;
    constexpr int PHASES = KT / 64;                  // 24 (conv1) / 12 (conv2)

    const int blocksPerBatch = T_ / MT;              // 8
    const int b  = blockIdx.x / blocksPerBatch;
    const int t0 = (blockIdx.x % blocksPerBatch) * MT;
    const int l  = threadIdx.x & 63;
    const int wv = threadIdx.x >> 6;                 // 0..7
    const int fg = wv & 3;
    const int rg = wv >> 2;

    // ---- stage A rows t0-1 .. t0+MT into LDS as bf16, swizzled ----
    constexpr int CH = (MT + 2) * IN_D / 8;
    for (int c = threadIdx.x; c < CH; c += 512) {
        int j  = c / (IN_D / 8);
        int d8 = (c % (IN_D / 8)) * 8;
        int t  = t0 - 1 + j;
        uint4 pk = make_uint4(0u, 0u, 0u, 0u);
        if (t >= 0 && t < T_) {
            if constexpr (std::is_same_v<InT, float>) {
                const float4* src = reinterpret_cast<const float4*>(&x[((size_t)b * T_ + t) * IN_D + d8]);
                float4 a0 = src[0], a1 = src[1];
                pk.x = (unsigned)f2bf(a0.x) | ((unsigned)f2bf(a0.y) << 16);
                pk.y = (unsigned)f2bf(a0.z) | ((unsigned)f2bf(a0.w) << 16);
                pk.z = (unsigned)f2bf(a1.x) | ((unsigned)f2bf(a1.y) << 16);
                pk.w = (unsigned)f2bf(a1.z) | ((unsigned)f2bf(a1.w) << 16);
            } else {
                pk = *reinterpret_cast<const uint4*>(&x[((size_t)b * T_ + t) * IN_D + d8]);
            }
        }
        int byte = ((j * IN_D + d8) * 2) ^ ((j & 7) << 4);
        *reinterpret_cast<uint4*>(&sm.xs_raw[byte]) = pk;
    }

    float bv[4], gv[4], bev[4], wlv[4];
#pragma unroll
    for (int n = 0; n < 4; ++n) {
        int f = fg * 64 + n * 16 + (l & 15);
        bv[n] = bias[f]; gv[n] = gamma[f]; bev[n] = beta[f];
        if constexpr (FUSE_DUR) wlv[n] = wl[f];
    }
    float blv = 0.f;
    if constexpr (FUSE_DUR) blv = bl[0];

    asm volatile("s_waitcnt vmcnt(0)" ::: "memory");   // ledger baseline
    __syncthreads();

    // ---- gather assignment: GROWS = 2*GP consecutive rows per wave ----
    constexpr int GROWS = 2 * GP;
    const int rbase = GBASE + (blockIdx.x * 8 + wv) * GROWS;
    int gidxv = gidx[rbase + min(l, GROWS - 1)];       // 1 vmem load
    MEMPIN();

    // ---- B staging: [256 f][8 kg][8 k], slot XOR kg^(f&7); gll dest linear ----
    const int sbase = wv * 4;
    auto stageB = [&](int ph, int buf) {
        int p = ph < PHASES ? ph : PHASES - 1;
        unsigned short* lb = &sm.xsB[buf * 16384];
#pragma unroll
        for (int i = 0; i < 4; ++i) {
            int s = sbase + i;
            int c = s * 64 + l;
            int f = c >> 3;
            int kg = (c & 7) ^ (f & 7);
            const unsigned short* src = wT + (size_t)f * KT + p * 64 + kg * 8;
            GLL16(src, lb + s * 512);
        }
    };
    auto loadBfrag = [&](bf16x8* dst, int buf, int kk2) {
#pragma unroll
        for (int n = 0; n < 4; ++n) {
            int f  = fg * 64 + n * 16 + (l & 15);
            int kg = kk2 * 4 + (l >> 4);
            dst[n] = *reinterpret_cast<const bf16x8*>(&sm.xsB[buf * 16384 + f * 64 + ((kg ^ (f & 7)) * 8)]);
        }
    };
    const int k_lane = (l >> 4) * 8;
    auto loadA = [&](bf16x8* dst, int kk) {
        int kp = kk / IN_D;
        int dbase = (kk % IN_D) + k_lane;
#pragma unroll
        for (int m = 0; m < 2; ++m) {
            int j = rg * 32 + m * 16 + (l & 15) + kp;
            int byte = ((j * IN_D + dbase) * 2) ^ ((j & 7) << 4);
            dst[m] = *reinterpret_cast<const bf16x8*>(&sm.xs_raw[byte]);
        }
    };

    // gather set load/store: 2 rows/set, 2 dwordx4 per lane per row
    float4 ga[3][2][2];
    auto loadSet = [&](int slot, int s) {
#pragma unroll
        for (int i = 0; i < 2; ++i) {
            int li = 2 * s + i;                        // always < GROWS (caller guards)
            int ix = __shfl(gidxv, li);
            int r  = rbase + li;
            if (ix >= 0) {
                const float* src = xf + ((size_t)(r >> 12) * T_ + ix) * D_ + l * 4;
                ga[slot][i][0] = *reinterpret_cast<const float4*>(src);
                ga[slot][i][1] = *reinterpret_cast<const float4*>(src + 256);
            } else {
                ga[slot][i][0] = make_float4(0.f, 0.f, 0.f, 0.f);
                ga[slot][i][1] = make_float4(0.f, 0.f, 0.f, 0.f);
            }
        }
    };
    auto storeSet = [&](int slot, int s) {
#pragma unroll
        for (int i = 0; i < 2; ++i) {
            int r = rbase + 2 * s + i;
            float* d = gout + (size_t)r * D_ + l * 4;
            *reinterpret_cast<float4*>(d)       = ga[slot][i][0];
            *reinterpret_cast<float4*>(d + 256) = ga[slot][i][1];
        }
    };

    f32x4 acc[2][4];
#pragma unroll
    for (int m = 0; m < 2; ++m)
#pragma unroll
        for (int n = 0; n < 4; ++n) acc[m][n] = (f32x4){0.f, 0.f, 0.f, 0.f};

    // ---- prologue: [gidx][G0][G1][L0][L1][L2], order pinned ----
    stageB(0, 0);  MEMPIN();
    stageB(1, 1);  MEMPIN();
    loadSet(0, 0); MEMPIN();
    loadSet(1, 1); MEMPIN();
    loadSet(2, 2); MEMPIN();

    // ---- phase loop; ladder = ops issued after G_p (stores excluded from the
    //      critical wait by body order), constant-folded under full unroll ----
#pragma unroll
    for (int p = 0; p < PHASES; ++p) {
        const int nw = (p == 0) ? 16 : (p == 1) ? 24
                     : (((p - 2 < GP) ? 4 : 0) + ((p + 1 < GP) ? 4 : 0) + 4 +
                        ((p - 1 < GP) ? 4 : 0) + ((p + 2 < GP) ? 4 : 0));
        if      (nw == 24) asm volatile("s_waitcnt vmcnt(24)" ::: "memory");
        else if (nw == 20) asm volatile("s_waitcnt vmcnt(20)" ::: "memory");
        else if (nw == 16) asm volatile("s_waitcnt vmcnt(16)" ::: "memory");
        else if (nw == 12) asm volatile("s_waitcnt vmcnt(12)" ::: "memory");
        else if (nw == 8)  asm volatile("s_waitcnt vmcnt(8)"  ::: "memory");
        else               asm volatile("s_waitcnt vmcnt(4)"  ::: "memory");
        BARRIER();
        int buf = p & 1;
#pragma unroll
        for (int kk2 = 0; kk2 < 2; ++kk2) {
            int kk = p * 64 + kk2 * 32;
            bf16x8 Bv[4], Av[2];
            loadBfrag(Bv, buf, kk2);
            loadA(Av, kk);
#pragma unroll
            for (int m = 0; m < 2; ++m)
#pragma unroll
                for (int n = 0; n < 4; ++n)
                    acc[m][n] = __builtin_amdgcn_mfma_f32_16x16x32_bf16(Av[m], Bv[n], acc[m][n], 0, 0, 0);
        }
        BARRIER();
        // body: [G_{p+2}][S_p][L_{p+3}]
        stageB(p + 2, buf);                       MEMPIN();
        if (p < GP)     { storeSet(p % 3, p);     MEMPIN(); }
        if (p + 3 < GP) { loadSet((p + 3) % 3, p + 3); MEMPIN(); }
    }

    // ---- epilogue: bias, LN stats, LN+ReLU store, optional fused dur ----
#pragma unroll
    for (int m = 0; m < 2; ++m)
#pragma unroll
        for (int q = 0; q < 4; ++q) {
            float s = 0.f, s2 = 0.f;
#pragma unroll
            for (int n = 0; n < 4; ++n) {
                float v2 = acc[m][n][q] + bv[n];
                acc[m][n][q] = v2;
                s += v2; s2 += v2 * v2;
            }
#pragma unroll
            for (int o = 1; o < 16; o <<= 1) { s += __shfl_xor(s, o); s2 += __shfl_xor(s2, o); }
            int row = rg * 32 + m * 16 + (l >> 4) * 4 + q;   // C/D: col=l&15, row=(l>>4)*4+q
            if ((l & 15) == 0) { sm.red[row][fg * 2] = s; sm.red[row][fg * 2 + 1] = s2; }
        }
    __syncthreads();

#pragma unroll
    for (int m = 0; m < 2; ++m)
#pragma unroll
        for (int q = 0; q < 4; ++q) {
            int row = rg * 32 + m * 16 + (l >> 4) * 4 + q;
            float s  = sm.red[row][0] + sm.red[row][2] + sm.red[row][4] + sm.red[row][6];
            float s2 = sm.red[row][1] + sm.red[row][3] + sm.red[row][5] + sm.red[row][7];
            float mu  = s * (1.f / F_);
            float var = s2 * (1.f / F_) - mu * mu;
            float rs  = rsqrtf(var + EPS_);
            size_t rb2 = ((size_t)(b * T_ + t0 + row)) * F_;
            float part = 0.f;
#pragma unroll
            for (int n = 0; n < 4; ++n) {
                float y = (acc[m][n][q] - mu) * rs * gv[n] + bev[n];
                y = fmaxf(y, 0.f);
                outp[rb2 + fg * 64 + n * 16 + (l & 15)] = f2bf(y);
                if constexpr (FUSE_DUR) part = fmaf(y, wlv[n], part);
            }
            if constexpr (FUSE_DUR) {
#pragma unroll
                for (int o = 1; o < 16; o <<= 1) part += __shfl_xor(part, o);
                if ((l & 15) == 0) sm.redD[row][fg] = part;
            }
        }

    if constexpr (FUSE_DUR) {
        __syncthreads();
        if (threadIdx.x < MT) {
            float s = sm.redD[threadIdx.x][0] + sm.redD[threadIdx.x][1]
                    + sm.redD[threadIdx.x][2] + sm.redD[threadIdx.x][3] + blv;
            dur[(size_t)b * T_ + t0 + threadIdx.x] = fmaxf(s, 0.f);
        }
    }
}

// ---------------------------------------------------------------------------
// One cooperative kernel: P0 prep (weights + cumsum/gidx) -> sync ->
// conv1 + gather[0,90112) -> sync -> conv2 + dur + gather[90112,131072).
// 256 blocks x 512 thr, 136 KB LDS -> 1 block/CU, co-resident.
// ---------------------------------------------------------------------------
__global__ __launch_bounds__(512, 2)
void mega_kernel(const float* __restrict__ x, const int* __restrict__ target,
                 const float* __restrict__ w1, const float* __restrict__ b1,
                 const float* __restrict__ g1, const float* __restrict__ be1,
                 const float* __restrict__ w2, const float* __restrict__ b2,
                 const float* __restrict__ g2, const float* __restrict__ be2,
                 const float* __restrict__ wl, const float* __restrict__ bl,
                 float* __restrict__ out, float* __restrict__ dur,
                 unsigned short* __restrict__ w1T, unsigned short* __restrict__ w2T,
                 unsigned short* __restrict__ h1, unsigned short* __restrict__ h2,
                 int* __restrict__ gidx)
{
    __shared__ SharedMem sm;
    cg::grid_group grid = cg::this_grid();

    // ================= P0: prep =================
    {
        constexpr int NW1 = 3 * D_ * F_;              // 393216
        constexpr int NW2 = 3 * F_ * F_;              // 196608
        int gtid = blockIdx.x * 512 + threadIdx.x;    // 131072 threads
        for (int i = gtid; i < NW1 + NW2; i += 256 * 512) {
            if (i < NW1) {
                int kk = i / F_, f = i % F_;
                w1T[(size_t)f * (3 * D_) + kk] = f2bf(w1[i]);
            } else {
                int j = i - NW1;
                int kk = j / F_, f = j % F_;
                w2T[(size_t)f * (3 * F_) + kk] = f2bf(w2[j]);
            }
        }
        if (blockIdx.x < B_) {
            int* lcum = (int*)sm.xs_raw;
            int* wpre = (int*)sm.redD;
            int b = blockIdx.x;
            int tid = threadIdx.x;
            int lane = tid & 63, w = tid >> 6;
            int v = target[b * T_ + tid];
#pragma unroll
            for (int o = 1; o < 64; o <<= 1) { int u = __shfl_up(v, o); if (lane >= o) v += u; }
            if (lane == 63) wpre[w] = v;
            __syncthreads();
            int base = 0;
#pragma unroll
            for (int i = 0; i < 8; ++i) if (i < w) base += wpre[i];
            lcum[tid] = base + v;
            __syncthreads();
            int total = lcum[T_ - 1];
#pragma unroll
            for (int k = 0; k < MEL / 512; ++k) {
                int pos = tid + k * 512;
                int lo = 0, hi = T_;
                while (lo < hi) { int mid = (lo + hi) >> 1; if (lcum[mid] <= pos) lo = mid + 1; else hi = mid; }
                gidx[b * MEL + pos] = (pos < total) ? min(lo, T_ - 1) : -1;
            }
        }
    }
    __threadfence();
    grid.sync();

    // ================= P1: conv1 + gather rows [0, 90112) =================
    conv_phase<D_, float, false, 22, 0>(sm, x, w1T, b1, g1, be1, h1,
                                        nullptr, nullptr, nullptr, x, gidx, out);
    __threadfence();
    grid.sync();

    // ================= P2: conv2 + dur + gather rows [90112, 131072) =================
    conv_phase<F_, unsigned short, true, 10, 90112>(sm, h1, w2T, b2, g2, be2, h2,
                                                    wl, bl, dur, x, gidx, out);
}

extern "C" void kernel_launch(void* const* d_in, const int* in_sizes, int n_in,
                              void* d_out, int out_size, void* d_ws, size_t ws_size,
                              hipStream_t stream)
{
    const float* x      = (const float*)d_in[0];
    const int*   target = (const int*)d_in[1];
    const float* w1  = (const float*)d_in[3];
    const float* b1  = (const float*)d_in[4];
    const float* g1  = (const float*)d_in[5];
    const float* be1 = (const float*)d_in[6];
    const float* w2  = (const float*)d_in[7];
    const float* b2  = (const float*)d_in[8];
    const float* g2  = (const float*)d_in[9];
    const float* be2 = (const float*)d_in[10];
    const float* wl  = (const float*)d_in[11];
    const float* bl  = (const float*)d_in[12];

    float* out = (float*)d_out;                        // (B, MEL, D)
    float* dur = out + (size_t)B_ * MEL * D_;          // (B, T)

    char* ws = (char*)d_ws;
    unsigned short* w1T = (unsigned short*)ws;         ws += (size_t)F_ * (3 * D_) * 2;
    unsigned short* w2T = (unsigned short*)ws;         ws += (size_t)F_ * (3 * F_) * 2;
    unsigned short* h1  = (unsigned short*)ws;         ws += (size_t)B_ * T_ * F_ * 2;
    unsigned short* h2  = (unsigned short*)ws;         ws += (size_t)B_ * T_ * F_ * 2;
    int*            gidx = (int*)ws;                   // B_*MEL ints

    void* args[] = {
        (void*)&x, (void*)&target,
        (void*)&w1, (void*)&b1, (void*)&g1, (void*)&be1,
        (void*)&w2, (void*)&b2, (void*)&g2, (void*)&be2,
        (void*)&wl, (void*)&bl,
        (void*)&out, (void*)&dur,
        (void*)&w1T, (void*)&w2T, (void*)&h1, (void*)&h2, (void*)&gidx
    };
    hipLaunchCooperativeKernel((const void*)mega_kernel, dim3(B_ * (T_ / 64)), dim3(512),
                               args, 0, stream);
}

// Round 9
// 179.496 us; speedup vs baseline: 1.5716x; 1.5716x over previous
//
#include <hip/hip_runtime.h>
#include <type_traits>

#define B_   32
#define T_   512
#define D_   512
#define F_   256
#define MEL  4096
#define EPS_ 1e-5f

typedef __attribute__((ext_vector_type(8))) short bf16x8;
typedef __attribute__((ext_vector_type(4))) float f32x4;

#define GLL16(gp, lp) \
    __builtin_amdgcn_global_load_lds((const __attribute__((address_space(1))) void*)(gp), \
                                     (__attribute__((address_space(3))) void*)(lp), 16, 0, 0)
#define BARRIER() do { asm volatile("" ::: "memory"); __builtin_amdgcn_s_barrier(); \
                       asm volatile("" ::: "memory"); } while (0)
#define MEMPIN() asm volatile("" ::: "memory")

__device__ inline unsigned short f2bf(float f) {
    unsigned u = __float_as_uint(f);
    unsigned r = (u + 0x7fff + ((u >> 16) & 1)) >> 16;   // RNE
    return (unsigned short)r;
}

// ---------------------------------------------------------------------------
// prep: weight transpose/convert (blocks 0..2303) + per-batch cumsum & idx
// precompute (blocks 2304..2335). gidx[b][pos] = source row, or -1 (masked).
// ---------------------------------------------------------------------------
#define PREP_WBLOCKS 2304   // (3*D_*F_ + 3*F_*F_) / 256

__global__ __launch_bounds__(256)
void prep_kernel(const float* __restrict__ w1, const float* __restrict__ w2,
                 const int* __restrict__ tgt,
                 unsigned short* __restrict__ w1T, unsigned short* __restrict__ w2T,
                 int* __restrict__ gidx)
{
    __shared__ int lcum[T_];
    __shared__ int wsum[4];

    int bid = blockIdx.x;
    int tid = threadIdx.x;
    if (bid < PREP_WBLOCKS) {
        int idx = bid * 256 + tid;
        if (idx < 3 * D_ * F_) {
            int kk = idx / F_, f = idx % F_;
            w1T[(size_t)f * (3 * D_) + kk] = f2bf(w1[idx]);
        } else {
            int j = idx - 3 * D_ * F_;
            int kk = j / F_, f = j % F_;
            w2T[(size_t)f * (3 * F_) + kk] = f2bf(w2[j]);
        }
        return;
    }

    int b = bid - PREP_WBLOCKS;
    int t0 = tid * 2;
    int a0 = tgt[b * T_ + t0], a1 = tgt[b * T_ + t0 + 1];
    int lane = tid & 63, w = tid >> 6;
    int v = a0 + a1;
#pragma unroll
    for (int o = 1; o < 64; o <<= 1) { int u = __shfl_up(v, o); if (lane >= o) v += u; }
    if (lane == 63) wsum[w] = v;
    __syncthreads();
    int base = 0;
#pragma unroll
    for (int i = 0; i < 4; ++i) if (i < w) base += wsum[i];
    int incl = base + v;
    lcum[t0]     = incl - a1;
    lcum[t0 + 1] = incl;
    __syncthreads();

    int total = lcum[T_ - 1];
#pragma unroll
    for (int k = 0; k < MEL / 256; ++k) {
        int pos = tid + k * 256;
        int lo = 0, hi = T_;
        while (lo < hi) { int mid = (lo + hi) >> 1; if (lcum[mid] <= pos) lo = mid + 1; else hi = mid; }
        gidx[b * MEL + pos] = (pos < total) ? min(lo, T_ - 1) : -1;
    }
}

// ---------------------------------------------------------------------------
// Conv1d(K=3,SAME)+bias+LN+ReLU via bf16 MFMA + gather rows riding the same
// counted-vmcnt pipeline. MT=32 rows/block -> grid 512 = 2 blocks/CU (TLP).
// 512 thr = 8 waves (2 rowgroups x 4 fgroups), acc[1][4] per wave.
// A: monolithic LDS tile, XOR-swizzled. B: 32-k slices, double-buffered via
// global_load_lds into [kg][f][8k] layout (bank-conflict-free frag reads).
// Gather: 1 row/set, ALWAYS loaded (clamped idx; zeroed at store) so the
// per-wave vmcnt ledger is exact. Body: [G_{p+2}][S_p][L_{p+3}].
// Ledger: prologue [gidx(1)|G0(2)|G1(2)|L0(2)|L1(2)|L2(2)];
// p=0:8, p=1:12, steady 2*(1+(p-2<GP)+(p+1<GP)+(p-1<GP)+(p+2<GP)).
// ---------------------------------------------------------------------------
template<int IN_D, typename InT, bool FUSE_DUR, int GP, int GBASE>
__global__ __launch_bounds__(512, 4)
void conv_mfma_kernel(const InT* __restrict__ x, const unsigned short* __restrict__ wT,
                      const float* __restrict__ bias, const float* __restrict__ gamma,
                      const float* __restrict__ beta, unsigned short* __restrict__ out,
                      const float* __restrict__ wl, const float* __restrict__ bl,
                      float* __restrict__ dur,
                      const float* __restrict__ xf, const int* __restrict__ gidx,
                      float* __restrict__ gout)
{
    constexpr int MT = 32;
    constexpr int KT = 3 * IN_D;
    constexpr int PHASES = KT / 32;                  // 48 (conv1) / 24 (conv2)

    __shared__ __align__(16) char xs_raw[(MT + 2) * IN_D * 2];
    __shared__ __align__(16) unsigned short xsB[2 * 8192];   // 2 x 16 KB B buffers
    __shared__ float red[MT][8];
    __shared__ float redD[MT][4];

    const int blocksPerBatch = T_ / MT;              // 16
    const int b  = blockIdx.x / blocksPerBatch;
    const int t0 = (blockIdx.x % blocksPerBatch) * MT;
    const int l  = threadIdx.x & 63;
    const int wv = threadIdx.x >> 6;                 // 0..7
    const int fg = wv & 3;
    const int rg = wv >> 2;

    // ---- stage A rows t0-1 .. t0+MT into LDS as bf16, swizzled ----
    constexpr int CH = (MT + 2) * IN_D / 8;
    for (int c = threadIdx.x; c < CH; c += 512) {
        int j  = c / (IN_D / 8);
        int d8 = (c % (IN_D / 8)) * 8;
        int t  = t0 - 1 + j;
        uint4 pk = make_uint4(0u, 0u, 0u, 0u);
        if (t >= 0 && t < T_) {
            if constexpr (std::is_same_v<InT, float>) {
                const float4* src = reinterpret_cast<const float4*>(&x[((size_t)b * T_ + t) * IN_D + d8]);
                float4 a0 = src[0], a1 = src[1];
                pk.x = (unsigned)f2bf(a0.x) | ((unsigned)f2bf(a0.y) << 16);
                pk.y = (unsigned)f2bf(a0.z) | ((unsigned)f2bf(a0.w) << 16);
                pk.z = (unsigned)f2bf(a1.x) | ((unsigned)f2bf(a1.y) << 16);
                pk.w = (unsigned)f2bf(a1.z) | ((unsigned)f2bf(a1.w) << 16);
            } else {
                pk = *reinterpret_cast<const uint4*>(&x[((size_t)b * T_ + t) * IN_D + d8]);
            }
        }
        int byte = ((j * IN_D + d8) * 2) ^ ((j & 7) << 4);
        *reinterpret_cast<uint4*>(&xs_raw[byte]) = pk;
    }

    float bv[4], gv[4], bev[4], wlv[4];
#pragma unroll
    for (int n = 0; n < 4; ++n) {
        int f = fg * 64 + n * 16 + (l & 15);
        bv[n] = bias[f]; gv[n] = gamma[f]; bev[n] = beta[f];
        if constexpr (FUSE_DUR) wlv[n] = wl[f];
    }
    float blv = 0.f;
    if constexpr (FUSE_DUR) blv = bl[0];

    asm volatile("s_waitcnt vmcnt(0)" ::: "memory");   // ledger baseline
    __syncthreads();

    // ---- gather assignment: GP consecutive rows per wave ----
    const int rbase = GBASE + (blockIdx.x * 8 + wv) * GP;
    int gidxv = gidx[rbase + min(l, GP - 1)];          // 1 vmem load
    MEMPIN();

    // ---- B staging: slice layout [kg(4)][f(256)][k(8)], linear gll dest ----
    auto stageB = [&](int ph, int buf) {
        int p = ph < PHASES ? ph : PHASES - 1;
        unsigned short* lb = &xsB[buf * 8192];
#pragma unroll
        for (int i = 0; i < 2; ++i) {
            int c  = i * 512 + wv * 64 + l;            // chunk id, lane-linear
            int f  = c & 255;
            int kg = c >> 8;
            const unsigned short* src = wT + (size_t)f * KT + p * 32 + kg * 8;
            GLL16(src, lb + (size_t)(i * 512 + wv * 64) * 8);
        }
    };
    auto loadBfrag = [&](bf16x8* dst, int buf) {
#pragma unroll
        for (int n = 0; n < 4; ++n) {
            int f  = fg * 64 + n * 16 + (l & 15);
            int kg = l >> 4;
            dst[n] = *reinterpret_cast<const bf16x8*>(&xsB[buf * 8192 + (kg * 256 + f) * 8]);
        }
    };
    const int k_lane = (l >> 4) * 8;
    auto loadA = [&](bf16x8* dst, int kk) {
        int kp = kk / IN_D;                            // conv tap 0..2
        int dbase = (kk % IN_D) + k_lane;
        int j = rg * 16 + (l & 15) + kp;
        int byte = ((j * IN_D + dbase) * 2) ^ ((j & 7) << 4);
        dst[0] = *reinterpret_cast<const bf16x8*>(&xs_raw[byte]);
    };

    // gather: 1 row/set, 2 dwordx4 per lane; ALWAYS load (exact ledger)
    float4 ga[3][2];
    auto loadSet = [&](int slot, int s) {
        int ix = __shfl(gidxv, s);
        int r  = rbase + s;
        const float* src = xf + ((size_t)(r >> 12) * T_ + max(ix, 0)) * D_ + l * 4;
        ga[slot][0] = *reinterpret_cast<const float4*>(src);
        ga[slot][1] = *reinterpret_cast<const float4*>(src + 256);
    };
    auto storeSet = [&](int slot, int s) {
        int ix = __shfl(gidxv, s);
        int r  = rbase + s;
        float4 a = ga[slot][0], c = ga[slot][1];
        if (ix < 0) { a = make_float4(0.f,0.f,0.f,0.f); c = make_float4(0.f,0.f,0.f,0.f); }
        float* d = gout + (size_t)r * D_ + l * 4;
        *reinterpret_cast<float4*>(d)       = a;
        *reinterpret_cast<float4*>(d + 256) = c;
    };

    f32x4 acc[4];
#pragma unroll
    for (int n = 0; n < 4; ++n) acc[n] = (f32x4){0.f, 0.f, 0.f, 0.f};

    // ---- prologue: [G0][G1][L0][L1][L2], order pinned ----
    stageB(0, 0);  MEMPIN();
    stageB(1, 1);  MEMPIN();
    loadSet(0, 0); MEMPIN();
    loadSet(1, 1); MEMPIN();
    loadSet(2, 2); MEMPIN();

    // ---- phase loop ----
#pragma unroll
    for (int p = 0; p < PHASES; ++p) {
        const int nw = (p == 0) ? 8 : (p == 1) ? 12
                     : 2 * (1 + ((p - 2 < GP) ? 1 : 0) + ((p + 1 < GP) ? 1 : 0) +
                                ((p - 1 < GP) ? 1 : 0) + ((p + 2 < GP) ? 1 : 0));
        if      (nw == 12) asm volatile("s_waitcnt vmcnt(12)" ::: "memory");
        else if (nw == 10) asm volatile("s_waitcnt vmcnt(10)" ::: "memory");
        else if (nw == 8)  asm volatile("s_waitcnt vmcnt(8)"  ::: "memory");
        else if (nw == 6)  asm volatile("s_waitcnt vmcnt(6)"  ::: "memory");
        else if (nw == 4)  asm volatile("s_waitcnt vmcnt(4)"  ::: "memory");
        else               asm volatile("s_waitcnt vmcnt(2)"  ::: "memory");
        BARRIER();
        int buf = p & 1;
        {
            bf16x8 Bv[4], Av[1];
            loadBfrag(Bv, buf);
            loadA(Av, p * 32);
#pragma unroll
            for (int n = 0; n < 4; ++n)
                acc[n] = __builtin_amdgcn_mfma_f32_16x16x32_bf16(Av[0], Bv[n], acc[n], 0, 0, 0);
        }
        BARRIER();
        // body: [G_{p+2}][S_p][L_{p+3}]
        stageB(p + 2, buf);                            MEMPIN();
        if (p < GP)     { storeSet(p % 3, p);          MEMPIN(); }
        if (p + 3 < GP) { loadSet((p + 3) % 3, p + 3); MEMPIN(); }
    }

    // ---- epilogue: bias, LN stats, LN+ReLU store, optional fused dur ----
#pragma unroll
    for (int q = 0; q < 4; ++q) {
        float s = 0.f, s2 = 0.f;
#pragma unroll
        for (int n = 0; n < 4; ++n) {
            float v2 = acc[n][q] + bv[n];
            acc[n][q] = v2;
            s += v2; s2 += v2 * v2;
        }
#pragma unroll
        for (int o = 1; o < 16; o <<= 1) { s += __shfl_xor(s, o); s2 += __shfl_xor(s2, o); }
        int row = rg * 16 + (l >> 4) * 4 + q;          // C/D: col=l&15, row=(l>>4)*4+q
        if ((l & 15) == 0) { red[row][fg * 2] = s; red[row][fg * 2 + 1] = s2; }
    }
    __syncthreads();

#pragma unroll
    for (int q = 0; q < 4; ++q) {
        int row = rg * 16 + (l >> 4) * 4 + q;
        float s  = red[row][0] + red[row][2] + red[row][4] + red[row][6];
        float s2 = red[row][1] + red[row][3] + red[row][5] + red[row][7];
        float mu  = s * (1.f / F_);
        float var = s2 * (1.f / F_) - mu * mu;
        float rs  = rsqrtf(var + EPS_);
        size_t rb2 = ((size_t)(b * T_ + t0 + row)) * F_;
        float part = 0.f;
#pragma unroll
        for (int n = 0; n < 4; ++n) {
            float y = (acc[n][q] - mu) * rs * gv[n] + bev[n];
            y = fmaxf(y, 0.f);
            out[rb2 + fg * 64 + n * 16 + (l & 15)] = f2bf(y);
            if constexpr (FUSE_DUR) part = fmaf(y, wlv[n], part);
        }
        if constexpr (FUSE_DUR) {
#pragma unroll
            for (int o = 1; o < 16; o <<= 1) part += __shfl_xor(part, o);
            if ((l & 15) == 0) redD[row][fg] = part;
        }
    }

    if constexpr (FUSE_DUR) {
        __syncthreads();
        if (threadIdx.x < MT) {
            float s = redD[threadIdx.x][0] + redD[threadIdx.x][1]
                    + redD[threadIdx.x][2] + redD[threadIdx.x][3] + blv;
            dur[(size_t)b * T_ + t0 + threadIdx.x] = fmaxf(s, 0.f);
        }
    }
}

extern "C" void kernel_launch(void* const* d_in, const int* in_sizes, int n_in,
                              void* d_out, int out_size, void* d_ws, size_t ws_size,
                              hipStream_t stream)
{
    const float* x      = (const float*)d_in[0];
    const int*   target = (const int*)d_in[1];
    const float* w1  = (const float*)d_in[3];
    const float* b1  = (const float*)d_in[4];
    const float* g1  = (const float*)d_in[5];
    const float* be1 = (const float*)d_in[6];
    const float* w2  = (const float*)d_in[7];
    const float* b2  = (const float*)d_in[8];
    const float* g2  = (const float*)d_in[9];
    const float* be2 = (const float*)d_in[10];
    const float* wl  = (const float*)d_in[11];
    const float* bl  = (const float*)d_in[12];

    float* out = (float*)d_out;                        // (B, MEL, D)
    float* dur = out + (size_t)B_ * MEL * D_;          // (B, T)

    char* ws = (char*)d_ws;
    unsigned short* w1T = (unsigned short*)ws;         ws += (size_t)F_ * (3 * D_) * 2;
    unsigned short* w2T = (unsigned short*)ws;         ws += (size_t)F_ * (3 * F_) * 2;
    unsigned short* h1  = (unsigned short*)ws;         ws += (size_t)B_ * T_ * F_ * 2;
    unsigned short* h2  = (unsigned short*)ws;         ws += (size_t)B_ * T_ * F_ * 2;
    int*            gidx = (int*)ws;                   // B_*MEL ints

    prep_kernel<<<PREP_WBLOCKS + B_, 256, 0, stream>>>(w1, w2, target, w1T, w2T, gidx);

    // gather rows: conv1 carries 512*8*22 = 90112, conv2 carries 512*8*10 = 40960.
    conv_mfma_kernel<D_, float, false, 22, 0><<<B_ * (T_ / 32), 512, 0, stream>>>(
        x, w1T, b1, g1, be1, h1, nullptr, nullptr, nullptr, x, gidx, out);
    conv_mfma_kernel<F_, unsigned short, true, 10, 90112><<<B_ * (T_ / 32), 512, 0, stream>>>(
        h1, w2T, b2, g2, be2, h2, wl, bl, dur, x, gidx, out);
}

// Round 10
// 97.434 us; speedup vs baseline: 2.8953x; 1.8422x over previous
//
#include <hip/hip_runtime.h>
#include <type_traits>

#define B_   32
#define T_   512
#define D_   512
#define F_   256
#define MEL  4096
#define EPS_ 1e-5f

typedef __attribute__((ext_vector_type(8))) short bf16x8;
typedef __attribute__((ext_vector_type(4))) float f32x4;

#define GLL16(gp, lp) \
    __builtin_amdgcn_global_load_lds((const __attribute__((address_space(1))) void*)(gp), \
                                     (__attribute__((address_space(3))) void*)(lp), 16, 0, 0)
#define BARRIER() do { asm volatile("" ::: "memory"); __builtin_amdgcn_s_barrier(); \
                       asm volatile("" ::: "memory"); } while (0)
#define MEMPIN() asm volatile("" ::: "memory")

__device__ inline unsigned short f2bf(float f) {
    unsigned u = __float_as_uint(f);
    unsigned r = (u + 0x7fff + ((u >> 16) & 1)) >> 16;   // RNE
    return (unsigned short)r;
}

// ---------------------------------------------------------------------------
// prep: weight transpose/convert (blocks 0..2303) + per-batch cumsum & idx
// precompute (blocks 2304..2335). gidx[b][pos] = source row, or -1 (masked).
// ---------------------------------------------------------------------------
#define PREP_WBLOCKS 2304   // (3*D_*F_ + 3*F_*F_) / 256

__global__ __launch_bounds__(256)
void prep_kernel(const float* __restrict__ w1, const float* __restrict__ w2,
                 const int* __restrict__ tgt,
                 unsigned short* __restrict__ w1T, unsigned short* __restrict__ w2T,
                 int* __restrict__ gidx)
{
    __shared__ int lcum[T_];
    __shared__ int wsum[4];

    int bid = blockIdx.x;
    int tid = threadIdx.x;
    if (bid < PREP_WBLOCKS) {
        int idx = bid * 256 + tid;
        if (idx < 3 * D_ * F_) {
            int kk = idx / F_, f = idx % F_;
            w1T[(size_t)f * (3 * D_) + kk] = f2bf(w1[idx]);
        } else {
            int j = idx - 3 * D_ * F_;
            int kk = j / F_, f = j % F_;
            w2T[(size_t)f * (3 * F_) + kk] = f2bf(w2[j]);
        }
        return;
    }

    int b = bid - PREP_WBLOCKS;
    int t0 = tid * 2;
    int a0 = tgt[b * T_ + t0], a1 = tgt[b * T_ + t0 + 1];
    int lane = tid & 63, w = tid >> 6;
    int v = a0 + a1;
#pragma unroll
    for (int o = 1; o < 64; o <<= 1) { int u = __shfl_up(v, o); if (lane >= o) v += u; }
    if (lane == 63) wsum[w] = v;
    __syncthreads();
    int base = 0;
#pragma unroll
    for (int i = 0; i < 4; ++i) if (i < w) base += wsum[i];
    int incl = base + v;
    lcum[t0]     = incl - a1;
    lcum[t0 + 1] = incl;
    __syncthreads();

    int total = lcum[T_ - 1];
#pragma unroll
    for (int k = 0; k < MEL / 256; ++k) {
        int pos = tid + k * 256;
        int lo = 0, hi = T_;
        while (lo < hi) { int mid = (lo + hi) >> 1; if (lcum[mid] <= pos) lo = mid + 1; else hi = mid; }
        gidx[b * MEL + pos] = (pos < total) ? min(lo, T_ - 1) : -1;
    }
}

// ---------------------------------------------------------------------------
// Fused conv1d(K=3,SAME)+bias+LN+ReLU via bf16 MFMA, gather rows riding the
// same counted-vmcnt pipeline (R7 structure, MT=64, 8 waves = 2rg x 4fg).
// Body order [G_{p+2}][S_{p-1}][L_{p+2}]: stores get ~3 phases of drain slack
// so phase-top waits pace on gll, not store retirement.
// Ledger (exact, stores count in vmcnt): prologue [gidx|G0|G1|L0|L1];
// p=0: 12, p=1: 16, p>=2: 4*(1+[0<=p-3<GP]+[p<GP]+[0<=p-2<GP]+[p+1<GP]).
// Set s (2 rows) loaded at body s-2, stored at body s+1, slot s%3.
// If GP == PHASES the last set is stored after the loop.
// ---------------------------------------------------------------------------
template<int IN_D, typename InT, bool FUSE_DUR, int GP, int GBASE>
__global__ __launch_bounds__(512)
void conv_mfma_kernel(const InT* __restrict__ x, const unsigned short* __restrict__ wT,
                      const float* __restrict__ bias, const float* __restrict__ gamma,
                      const float* __restrict__ beta, unsigned short* __restrict__ out,
                      const float* __restrict__ wl, const float* __restrict__ bl,
                      float* __restrict__ dur,
                      const float* __restrict__ xf, const int* __restrict__ gidx,
                      float* __restrict__ gout)
{
    constexpr int MT = 64;
    constexpr int KT = 3 * IN_D;
    constexpr int PHASES = KT / 64;                  // 24 (conv1) / 12 (conv2)

    __shared__ __align__(16) char xs_raw[(MT + 2) * IN_D * 2];
    __shared__ __align__(16) unsigned short xsB[2 * 16384];   // 2 x 32 KB B buffers
    __shared__ float red[MT][8];
    __shared__ float redD[MT][4];

    const int blocksPerBatch = T_ / MT;              // 8
    const int b  = blockIdx.x / blocksPerBatch;
    const int t0 = (blockIdx.x % blocksPerBatch) * MT;
    const int l  = threadIdx.x & 63;
    const int wv = threadIdx.x >> 6;                 // 0..7
    const int fg = wv & 3;
    const int rg = wv >> 2;

    // ---- stage A rows t0-1 .. t0+MT into LDS as bf16, swizzled ----
    constexpr int CH = (MT + 2) * IN_D / 8;
    for (int c = threadIdx.x; c < CH; c += 512) {
        int j  = c / (IN_D / 8);
        int d8 = (c % (IN_D / 8)) * 8;
        int t  = t0 - 1 + j;
        uint4 pk = make_uint4(0u, 0u, 0u, 0u);
        if (t >= 0 && t < T_) {
            if constexpr (std::is_same_v<InT, float>) {
                const float4* src = reinterpret_cast<const float4*>(&x[((size_t)b * T_ + t) * IN_D + d8]);
                float4 a0 = src[0], a1 = src[1];
                pk.x = (unsigned)f2bf(a0.x) | ((unsigned)f2bf(a0.y) << 16);
                pk.y = (unsigned)f2bf(a0.z) | ((unsigned)f2bf(a0.w) << 16);
                pk.z = (unsigned)f2bf(a1.x) | ((unsigned)f2bf(a1.y) << 16);
                pk.w = (unsigned)f2bf(a1.z) | ((unsigned)f2bf(a1.w) << 16);
            } else {
                pk = *reinterpret_cast<const uint4*>(&x[((size_t)b * T_ + t) * IN_D + d8]);
            }
        }
        int byte = ((j * IN_D + d8) * 2) ^ ((j & 7) << 4);
        *reinterpret_cast<uint4*>(&xs_raw[byte]) = pk;
    }

    float bv[4], gv[4], bev[4], wlv[4];
#pragma unroll
    for (int n = 0; n < 4; ++n) {
        int f = fg * 64 + n * 16 + (l & 15);
        bv[n] = bias[f]; gv[n] = gamma[f]; bev[n] = beta[f];
        if constexpr (FUSE_DUR) wlv[n] = wl[f];
    }
    float blv = 0.f;
    if constexpr (FUSE_DUR) blv = bl[0];

    asm volatile("s_waitcnt vmcnt(0)" ::: "memory");   // ledger baseline
    __syncthreads();

    // ---- gather assignment: GROWS = 2*GP consecutive rows per wave ----
    constexpr int GROWS = 2 * GP;
    const int rbase = GBASE + (blockIdx.x * 8 + wv) * GROWS;
    int gidxv = gidx[rbase + min(l, GROWS - 1)];       // 1 vmem load
    MEMPIN();

    // ---- B staging: [256 f][8 kg][8 k], slot XOR kg^(f&7); gll dest linear ----
    const int sbase = wv * 4;
    auto stageB = [&](int ph, int buf) {
        int p = ph < PHASES ? ph : PHASES - 1;
        unsigned short* lb = &xsB[buf * 16384];
#pragma unroll
        for (int i = 0; i < 4; ++i) {
            int s = sbase + i;
            int c = s * 64 + l;
            int f = c >> 3;
            int kg = (c & 7) ^ (f & 7);
            const unsigned short* src = wT + (size_t)f * KT + p * 64 + kg * 8;
            GLL16(src, lb + s * 512);
        }
    };
    auto loadBfrag = [&](bf16x8* dst, int buf, int kk2) {
#pragma unroll
        for (int n = 0; n < 4; ++n) {
            int f  = fg * 64 + n * 16 + (l & 15);
            int kg = kk2 * 4 + (l >> 4);
            dst[n] = *reinterpret_cast<const bf16x8*>(&xsB[buf * 16384 + f * 64 + ((kg ^ (f & 7)) * 8)]);
        }
    };
    const int k_lane = (l >> 4) * 8;
    auto loadA = [&](bf16x8* dst, int kk) {
        int kp = kk / IN_D;
        int dbase = (kk % IN_D) + k_lane;
#pragma unroll
        for (int m = 0; m < 2; ++m) {
            int j = rg * 32 + m * 16 + (l & 15) + kp;
            int byte = ((j * IN_D + dbase) * 2) ^ ((j & 7) << 4);
            dst[m] = *reinterpret_cast<const bf16x8*>(&xs_raw[byte]);
        }
    };

    // gather set load/store: 2 rows/set, 2 dwordx4 per lane per row.
    // ALWAYS load (clamped idx) so the per-wave vmcnt ledger is exact.
    float4 ga[3][2][2];
    auto loadSet = [&](int slot, int s) {
#pragma unroll
        for (int i = 0; i < 2; ++i) {
            int li = 2 * s + i;
            int ix = __shfl(gidxv, li);
            int r  = rbase + li;
            const float* src = xf + ((size_t)(r >> 12) * T_ + max(ix, 0)) * D_ + l * 4;
            ga[slot][i][0] = *reinterpret_cast<const float4*>(src);
            ga[slot][i][1] = *reinterpret_cast<const float4*>(src + 256);
        }
    };
    auto storeSet = [&](int slot, int s) {
#pragma unroll
        for (int i = 0; i < 2; ++i) {
            int li = 2 * s + i;
            int ix = __shfl(gidxv, li);
            int r  = rbase + li;
            float4 a = ga[slot][i][0], c = ga[slot][i][1];
            if (ix < 0) { a = make_float4(0.f,0.f,0.f,0.f); c = make_float4(0.f,0.f,0.f,0.f); }
            float* d = gout + (size_t)r * D_ + l * 4;
            *reinterpret_cast<float4*>(d)       = a;
            *reinterpret_cast<float4*>(d + 256) = c;
        }
    };

    f32x4 acc[2][4];
#pragma unroll
    for (int m = 0; m < 2; ++m)
#pragma unroll
        for (int n = 0; n < 4; ++n) acc[m][n] = (f32x4){0.f, 0.f, 0.f, 0.f};

    // ---- prologue: [gidx][G0][G1][L0][L1], order pinned; set 2 loads in body 0 ----
    stageB(0, 0);  MEMPIN();
    stageB(1, 1);  MEMPIN();
    loadSet(0, 0); MEMPIN();
    loadSet(1, 1); MEMPIN();

    // ---- phase loop ----
#pragma unroll
    for (int p = 0; p < PHASES; ++p) {
        const int nw = (p == 0) ? 12 : (p == 1) ? 16
                     : 4 * (1 + ((p >= 3 && p - 3 < GP) ? 1 : 0) + ((p < GP) ? 1 : 0) +
                                ((p - 2 < GP) ? 1 : 0) + ((p + 1 < GP) ? 1 : 0));
        if      (nw == 20) asm volatile("s_waitcnt vmcnt(20)" ::: "memory");
        else if (nw == 16) asm volatile("s_waitcnt vmcnt(16)" ::: "memory");
        else if (nw == 12) asm volatile("s_waitcnt vmcnt(12)" ::: "memory");
        else if (nw == 8)  asm volatile("s_waitcnt vmcnt(8)"  ::: "memory");
        else               asm volatile("s_waitcnt vmcnt(4)"  ::: "memory");
        BARRIER();
        int buf = p & 1;
#pragma unroll
        for (int kk2 = 0; kk2 < 2; ++kk2) {
            int kk = p * 64 + kk2 * 32;
            bf16x8 Bv[4], Av[2];
            loadBfrag(Bv, buf, kk2);
            loadA(Av, kk);
#pragma unroll
            for (int m = 0; m < 2; ++m)
#pragma unroll
                for (int n = 0; n < 4; ++n)
                    acc[m][n] = __builtin_amdgcn_mfma_f32_16x16x32_bf16(Av[m], Bv[n], acc[m][n], 0, 0, 0);
        }
        BARRIER();
        // body: [G_{p+2}][S_{p-1}][L_{p+2}]
        stageB(p + 2, buf);                                  MEMPIN();
        if (p >= 1 && p - 1 < GP) { storeSet((p - 1) % 3, p - 1); MEMPIN(); }
        if (p + 2 < GP)           { loadSet((p + 2) % 3, p + 2); MEMPIN(); }
    }
    if constexpr (GP >= PHASES) {                      // last set's store body doesn't exist
        storeSet((GP - 1) % 3, GP - 1);
    }

    // ---- epilogue: bias, LN stats, LN+ReLU store, optional fused dur ----
#pragma unroll
    for (int m = 0; m < 2; ++m)
#pragma unroll
        for (int q = 0; q < 4; ++q) {
            float s = 0.f, s2 = 0.f;
#pragma unroll
            for (int n = 0; n < 4; ++n) {
                float v2 = acc[m][n][q] + bv[n];
                acc[m][n][q] = v2;
                s += v2; s2 += v2 * v2;
            }
#pragma unroll
            for (int o = 1; o < 16; o <<= 1) { s += __shfl_xor(s, o); s2 += __shfl_xor(s2, o); }
            int row = rg * 32 + m * 16 + (l >> 4) * 4 + q;   // C/D: col=l&15, row=(l>>4)*4+q
            if ((l & 15) == 0) { red[row][fg * 2] = s; red[row][fg * 2 + 1] = s2; }
        }
    __syncthreads();

#pragma unroll
    for (int m = 0; m < 2; ++m)
#pragma unroll
        for (int q = 0; q < 4; ++q) {
            int row = rg * 32 + m * 16 + (l >> 4) * 4 + q;
            float s  = red[row][0] + red[row][2] + red[row][4] + red[row][6];
            float s2 = red[row][1] + red[row][3] + red[row][5] + red[row][7];
            float mu  = s * (1.f / F_);
            float var = s2 * (1.f / F_) - mu * mu;
            float rs  = rsqrtf(var + EPS_);
            size_t rb2 = ((size_t)(b * T_ + t0 + row)) * F_;
            float part = 0.f;
#pragma unroll
            for (int n = 0; n < 4; ++n) {
                float y = (acc[m][n][q] - mu) * rs * gv[n] + bev[n];
                y = fmaxf(y, 0.f);
                out[rb2 + fg * 64 + n * 16 + (l & 15)] = f2bf(y);
                if constexpr (FUSE_DUR) part = fmaf(y, wlv[n], part);
            }
            if constexpr (FUSE_DUR) {
#pragma unroll
                for (int o = 1; o < 16; o <<= 1) part += __shfl_xor(part, o);
                if ((l & 15) == 0) redD[row][fg] = part;
            }
        }

    if constexpr (FUSE_DUR) {
        __syncthreads();
        if (threadIdx.x < MT) {
            float s = redD[threadIdx.x][0] + redD[threadIdx.x][1]
                    + redD[threadIdx.x][2] + redD[threadIdx.x][3] + blv;
            dur[(size_t)b * T_ + t0 + threadIdx.x] = fmaxf(s, 0.f);
        }
    }
}

extern "C" void kernel_launch(void* const* d_in, const int* in_sizes, int n_in,
                              void* d_out, int out_size, void* d_ws, size_t ws_size,
                              hipStream_t stream)
{
    const float* x      = (const float*)d_in[0];
    const int*   target = (const int*)d_in[1];
    const float* w1  = (const float*)d_in[3];
    const float* b1  = (const float*)d_in[4];
    const float* g1  = (const float*)d_in[5];
    const float* be1 = (const float*)d_in[6];
    const float* w2  = (const float*)d_in[7];
    const float* b2  = (const float*)d_in[8];
    const float* g2  = (const float*)d_in[9];
    const float* be2 = (const float*)d_in[10];
    const float* wl  = (const float*)d_in[11];
    const float* bl  = (const float*)d_in[12];

    float* out = (float*)d_out;                        // (B, MEL, D)
    float* dur = out + (size_t)B_ * MEL * D_;          // (B, T)

    char* ws = (char*)d_ws;
    unsigned short* w1T = (unsigned short*)ws;         ws += (size_t)F_ * (3 * D_) * 2;
    unsigned short* w2T = (unsigned short*)ws;         ws += (size_t)F_ * (3 * F_) * 2;
    unsigned short* h1  = (unsigned short*)ws;         ws += (size_t)B_ * T_ * F_ * 2;
    unsigned short* h2  = (unsigned short*)ws;         ws += (size_t)B_ * T_ * F_ * 2;
    int*            gidx = (int*)ws;                   // B_*MEL ints

    prep_kernel<<<PREP_WBLOCKS + B_, 256, 0, stream>>>(w1, w2, target, w1T, w2T, gidx);

    // conv1 carries gather rows 0..98303 (24 sets x 2 rows x 8 waves x 256 blocks),
    // conv2 carries rows 98304..131071 (8 sets of 12 phases).
    conv_mfma_kernel<D_, float, false, 24, 0><<<B_ * (T_ / 64), 512, 0, stream>>>(
        x, w1T, b1, g1, be1, h1, nullptr, nullptr, nullptr, x, gidx, out);
    conv_mfma_kernel<F_, unsigned short, true, 8, 98304><<<B_ * (T_ / 64), 512, 0, stream>>>(
        h1, w2T, b2, g2, be2, h2, wl, bl, dur, x, gidx, out);
}